// Round 17
// baseline (465.878 us; speedup 1.0000x reference)
//
#include <hip/hip_runtime.h>
#include <stdint.h>
#include <string.h>

#define HID 2048

typedef __attribute__((ext_vector_type(8))) unsigned short u16x8;

__device__ __forceinline__ float h2f(unsigned short u){
  _Float16 f; __builtin_memcpy(&f, &u, 2); return (float)f;
}
__device__ __forceinline__ unsigned short f2h(float f){
  _Float16 g = (_Float16)f; unsigned short u; __builtin_memcpy(&u, &g, 2); return u;
}

// async global->LDS copy, 16B per lane; LDS dest = uniform base + lane*16 (HW)
typedef __attribute__((address_space(1))) const unsigned int gas_u32;
typedef __attribute__((address_space(3))) unsigned int las_u32;
__device__ __forceinline__ void gload16(const void* g, void* l){
  __builtin_amdgcn_global_load_lds((gas_u32*)g, (las_u32*)l, 16, 0, 0);
}

// ---------------- threefry2x32 (JAX partitionable; actions bit-exact R2-R16) ----------------
__device__ __forceinline__ uint32_t rotl32(uint32_t v, int r){ return (v<<r)|(v>>(32-r)); }

__device__ __forceinline__ void tf2x32(uint32_t k0, uint32_t k1, uint32_t x0, uint32_t x1,
                                       uint32_t& o0, uint32_t& o1){
  uint32_t ks2 = k0 ^ k1 ^ 0x1BD11BDAu;
  x0 += k0; x1 += k1;
  x0+=x1; x1=rotl32(x1,13); x1^=x0;
  x0+=x1; x1=rotl32(x1,15); x1^=x0;
  x0+=x1; x1=rotl32(x1,26); x1^=x0;
  x0+=x1; x1=rotl32(x1,6);  x1^=x0;
  x0+=k1; x1+=ks2+1u;
  x0+=x1; x1=rotl32(x1,17); x1^=x0;
  x0+=x1; x1=rotl32(x1,29); x1^=x0;
  x0+=x1; x1=rotl32(x1,16); x1^=x0;
  x0+=x1; x1=rotl32(x1,24); x1^=x0;
  x0+=ks2; x1+=k0+2u;
  x0+=x1; x1=rotl32(x1,13); x1^=x0;
  x0+=x1; x1=rotl32(x1,15); x1^=x0;
  x0+=x1; x1=rotl32(x1,26); x1^=x0;
  x0+=x1; x1=rotl32(x1,6);  x1^=x0;
  x0+=k0; x1+=k1+3u;
  x0+=x1; x1=rotl32(x1,17); x1^=x0;
  x0+=x1; x1=rotl32(x1,29); x1^=x0;
  x0+=x1; x1=rotl32(x1,16); x1^=x0;
  x0+=x1; x1=rotl32(x1,24); x1^=x0;
  x0+=k1; x1+=ks2+4u;
  x0+=x1; x1=rotl32(x1,13); x1^=x0;
  x0+=x1; x1=rotl32(x1,15); x1^=x0;
  x0+=x1; x1=rotl32(x1,26); x1^=x0;
  x0+=x1; x1=rotl32(x1,6);  x1^=x0;
  x0+=ks2; x1+=k0+5u;
  o0=x0; o1=x1;
}

__device__ __forceinline__ float wave_reduce(float v){
  #pragma unroll
  for (int s=32;s;s>>=1) v += __shfl_xor(v, s);
  return v;
}
__device__ __forceinline__ float dot4(float4 a, float4 b){
  return a.x*b.x + a.y*b.y + a.z*b.z + a.w*b.w;
}

// Wave-parallel sampler (R8-proven bit-exact). Returns argmax idx in ALL lanes.
__device__ __forceinline__ int sample_wave(float li, int kk, int lane,
                                           uint32_t* key_arr, int sidx, bool write,
                                           float* sc, int* actions, int slot){
  uint32_t k0 = key_arr[2*sidx], k1 = key_arr[2*sidx+1];
  uint32_t n0,n1,s0,s1;
  tf2x32(k0,k1,0u,0u,n0,n1);
  tf2x32(k0,k1,0u,1u,s0,s1);

  float m = li;
  #pragma unroll
  for (int s=32;s;s>>=1) m = fmaxf(m, __shfl_xor(m,s));
  float e = (lane<kk)? expf(li-m) : 0.f;
  float se = wave_reduce(e);
  float lse = logf(se);

  uint32_t y0,y1; tf2x32(s0,s1,0u,(uint32_t)lane,y0,y1);
  uint32_t bits = y0^y1;
  float f = __uint_as_float((bits>>9)|0x3f800000u) - 1.0f;
  float u = fmaxf(f, 1.17549435e-38f);
  float g = -logf(-logf(u));
  float z = (lane<kk)? li+g : -3.0e38f;
  int idx = lane;
  #pragma unroll
  for (int s=32;s;s>>=1){
    float zo = __shfl_xor(z,s); int io = __shfl_xor(idx,s);
    if (zo > z || (zo == z && io < idx)){ z = zo; idx = io; }
  }
  if (write){
    float lact = __shfl(li, idx);
    float lp = li-m-lse;
    float t = (lane<kk)? -lp*expf(lp) : 0.f;
    float ent = wave_reduce(t);
    if (lane==0){
      sc[0] += lact-m-lse;
      sc[1] += ent;
      actions[slot] = idx;
      key_arr[2*(sidx+1)]   = n0;
      key_arr[2*(sidx+1)+1] = n1;
    }
  }
  return idx;
}

// ---------------- weight conversion f32 -> f16 (Whh then Wh) ----------------
__global__ __launch_bounds__(256) void conv_kernel(const float* __restrict__ A,
                                                   const float* __restrict__ B,
                                                   unsigned short* __restrict__ oA,
                                                   unsigned short* __restrict__ oB,
                                                   int nA8, int nTot8){
  int i = blockIdx.x*256 + threadIdx.x;
  if (i >= nTot8) return;
  const float4* src; unsigned short* dst;
  if (i < nA8){ src = (const float4*)A + (size_t)i*2; dst = oA + (size_t)i*8; }
  else { int q = i - nA8; src = (const float4*)B + (size_t)q*2; dst = oB + (size_t)q*8; }
  float4 lo = src[0], hi = src[1];
  u16x8 o;
  o[0]=f2h(lo.x); o[1]=f2h(lo.y); o[2]=f2h(lo.z); o[3]=f2h(lo.w);
  o[4]=f2h(hi.x); o[5]=f2h(hi.y); o[6]=f2h(hi.z); o[7]=f2h(hi.w);
  *(u16x8*)dst = o;
}

// ---------------- eproj + init fold (R11-R16-proven) ----------------
__global__ __launch_bounds__(256) void eproj_kernel(const float* __restrict__ emb,
                                                    const float* __restrict__ Wq,
                                                    float* __restrict__ E,
                                                    float* __restrict__ h0,
                                                    float* __restrict__ c,
                                                    float* __restrict__ sc,
                                                    uint32_t* __restrict__ key_arr){
  if (blockIdx.x == 0){
    for (int r = threadIdx.x; r < HID; r += 256){ h0[r]=0.f; c[r]=0.f; }
    if (threadIdx.x == 0){ sc[0]=0.f; sc[1]=0.f; key_arr[0]=0u; key_arr[1]=42u; }
  }
  int w = (blockIdx.x*256 + threadIdx.x) >> 6;
  int lane = threadIdx.x & 63;
  if (w >= HID) return;
  const float4* W4 = (const float4*)(Wq + (size_t)w*HID);
  float acc[8];
  #pragma unroll
  for (int i=0;i<8;i++) acc[i]=0.f;
  #pragma unroll
  for (int it=0; it<8; ++it){
    float4 wv = W4[it*64 + lane];
    #pragma unroll
    for (int i=0;i<8;i++){
      float4 ev = ((const float4*)(emb + (size_t)i*HID))[it*64+lane];
      acc[i] += dot4(wv, ev);
    }
  }
  #pragma unroll
  for (int i=0;i<8;i++){
    float v = wave_reduce(acc[i]);
    if (lane==0) E[(size_t)i*HID + w] = v;
  }
}

// ---------------- pproj v5: async double-buffered LDS staging (R16-proven) ----------------
__global__ __launch_bounds__(256) void pproj_kernel(const float* __restrict__ Wih,
                                                    const float* __restrict__ emb,
                                                    const float* __restrict__ bih,
                                                    const float* __restrict__ bhh,
                                                    float* __restrict__ P){
  __shared__ float sbuf[2][19*256];   // 2 x 19456 B = 38912 B
  int tid = threadIdx.x, wid = tid>>6, lane = tid&63;
  int j0 = blockIdx.x*8 + wid*2, j1 = j0+1;
  float acc0[19], acc1[19];
  #pragma unroll
  for (int e=0;e<19;e++){ acc0[e]=0.f; acc1[e]=0.f; }

  for (int r = wid; r < 19; r += 4)
    gload16(emb + (size_t)r*HID + lane*4, (char*)&sbuf[0][r*256]);

  for (int ch = 0; ch < 8; ++ch){
    __syncthreads();
    if (ch < 7){
      float* nb = sbuf[(ch+1)&1];
      for (int r = wid; r < 19; r += 4)
        gload16(emb + (size_t)r*HID + (ch+1)*256 + lane*4, (char*)&nb[r*256]);
    }
    const float4* W0 = (const float4*)(Wih + (size_t)j0*HID + ch*256);
    const float4* W1 = (const float4*)(Wih + (size_t)j1*HID + ch*256);
    float4 w0 = W0[lane];
    float4 w1 = W1[lane];
    const float4* B4 = (const float4*)sbuf[ch&1];
    #pragma unroll
    for (int e=0;e<19;e++){
      float4 ev = B4[e*64 + lane];
      acc0[e] += dot4(w0, ev);
      acc1[e] += dot4(w1, ev);
    }
  }
  #pragma unroll
  for (int e=0;e<19;e++){ acc0[e]=wave_reduce(acc0[e]); acc1[e]=wave_reduce(acc1[e]); }
  if (lane==0){
    float b0 = bih[j0] + bhh[j0];
    float b1 = bih[j1] + bhh[j1];
    #pragma unroll
    for (int e=0;e<19;e++){
      P[(size_t)e*4*HID + j0] = acc0[e] + b0;
      P[(size_t)e*4*HID + j1] = acc1[e] + b1;
    }
    P[(size_t)19*4*HID + j0] = b0;
    P[(size_t)19*4*HID + j1] = b1;
  }
}

// ---------------- fused LSTM + pending sample (R15 matvec-first; R17 tail trims) ----------------
// New in R17 (bit-exact): (1) no sxi barrier -- tail threads are wave-0 lanes 0-3 and
// use sample_wave's register result directly; (2) all 20 candidate P rows prefetched to
// LDS before barrier 1; (3) c[t2] prefetched at kernel start.
__global__ __launch_bounds__(512,4) void lstm_fused(const unsigned short* __restrict__ Whh16,
                                                    const float* __restrict__ P,
                                                    const float* __restrict__ hin,
                                                    float* __restrict__ hout,
                                                    float* __restrict__ c,
                                                    const float* __restrict__ a,
                                                    const float* __restrict__ E,
                                                    const float* __restrict__ Wv,
                                                    const float* __restrict__ Wsoft,
                                                    const float* __restrict__ bsoft,
                                                    uint32_t* __restrict__ key_arr,
                                                    float* __restrict__ sc,
                                                    int* __restrict__ actions,
                                                    int mode, int k, int sidx, int slot,
                                                    int xoff, int xconst){
  __shared__ float4 hs4[512];
  __shared__ float red[8][4];
  __shared__ float slog[11];
  __shared__ float pf[20][16];   // candidate P rows: pf[cand][g*4 + tl]
  int tid = threadIdx.x, wid = tid>>6, lane = tid&63;
  hs4[tid] = ((const float4*)hin)[tid];
  int tl = wid & 3, khalf = wid >> 2;
  int t = blockIdx.x*4 + tl;
  // prefetch c for the tail (threads 0-3 own t2 = bx*4+tid; same thread writes it later)
  float cpre = 0.f;
  if (tid < 4) cpre = c[blockIdx.x*4 + tid];
  // prefetch ALL candidate P-row entries for this block into LDS (320 scattered L2 reads)
  if (tid < 320){
    int cand = tid >> 4, r = tid & 15;         // r = g*4 + tl2
    int g = r >> 2, tl2 = r & 3;
    pf[cand][r] = P[(size_t)cand*4*HID + g*HID + blockIdx.x*4 + tl2];
  }
  u16x8 wv[4][2];
  #pragma unroll
  for (int g=0; g<4; ++g){
    const u16x8* wr = (const u16x8*)(Whh16 + ((size_t)(g*HID + t))*HID) + khalf*128;
    wv[g][0] = wr[lane];
    wv[g][1] = wr[64 + lane];
  }
  __syncthreads();   // hs4 + pf ready

  // ---- matvec first (independent of pending sample) ----
  float4 hv[2][2];
  #pragma unroll
  for (int it=0; it<2; ++it){
    int idx = khalf*256 + (it*64+lane)*2;
    hv[it][0] = hs4[idx]; hv[it][1] = hs4[idx+1];
  }
  float acc[4] = {0.f,0.f,0.f,0.f};
  #pragma unroll
  for (int g=0; g<4; ++g){
    #pragma unroll
    for (int it=0; it<2; ++it){
      u16x8 w = wv[g][it];
      acc[g] += h2f(w[0])*hv[it][0].x + h2f(w[1])*hv[it][0].y
              + h2f(w[2])*hv[it][0].z + h2f(w[3])*hv[it][0].w
              + h2f(w[4])*hv[it][1].x + h2f(w[5])*hv[it][1].y
              + h2f(w[6])*hv[it][1].z + h2f(w[7])*hv[it][1].w;
    }
  }
  #pragma unroll
  for (int g=0; g<4; ++g){
    float v = wave_reduce(acc[g]);
    if (lane==0) red[wid][g] = v;
  }

  // ---- pending-sample logit rows (overlaps tail of other waves' matvec) ----
  if (mode == 1){
    if (wid < k){
      const float4* E4 = (const float4*)(E + (size_t)wid*HID);
      const float4* a4 = (const float4*)a;
      const float4* v4 = (const float4*)Wv;
      float s = 0.f;
      #pragma unroll
      for (int it=0; it<8; ++it){
        float4 ev = E4[it*64+lane];
        float4 av = a4[it*64+lane];
        float4 w  = v4[it*64+lane];
        s += tanhf(ev.x+av.x)*w.x + tanhf(ev.y+av.y)*w.y
           + tanhf(ev.z+av.z)*w.z + tanhf(ev.w+av.w)*w.w;
      }
      s = wave_reduce(s);
      if (lane==0) slog[wid] = s;
    }
  } else if (mode == 2){
    #pragma unroll
    for (int rep=0; rep<2; ++rep){
      int row = wid + rep*8;
      if (row < 11){
        const float4* W4 = (const float4*)(Wsoft + (size_t)row*HID);
        float s = 0.f;
        #pragma unroll
        for (int it=0; it<8; ++it) s += dot4(W4[it*64+lane], hs4[it*64+lane]);
        s = wave_reduce(s);
        if (lane==0) slog[row] = s + bsoft[row];
      }
    }
  }
  __syncthreads();   // red + slog ready (LAST barrier)

  // ---- wave 0 only: sample + pointwise tail (act lives in wave-0 registers) ----
  if (wid == 0){
    int xi;
    if (mode == 0){
      xi = xconst;
    } else {
      int kk = (mode==1) ? k : 11;
      float li = -3.0e38f;
      if (lane < kk){
        float raw = slog[lane];
        li = (mode==1) ? 2.5f*tanhf(raw*0.2f) : tanhf(raw*0.2f);
      }
      int act = sample_wave(li, kk, lane, key_arr, sidx, blockIdx.x==0,
                            sc, actions, slot);
      xi = act + xoff;
    }
    if (lane < 4){
      int t2 = blockIdx.x*4 + lane;
      const float* pr = pf[xi];
      float gi = red[lane][0]+red[lane+4][0] + pr[0*4+lane];
      float gf = red[lane][1]+red[lane+4][1] + pr[1*4+lane];
      float gg = red[lane][2]+red[lane+4][2] + pr[2*4+lane];
      float go = red[lane][3]+red[lane+4][3] + pr[3*4+lane];
      float si = 1.f/(1.f+expf(-gi));
      float sf = 1.f/(1.f+expf(-gf));
      float so = 1.f/(1.f+expf(-go));
      float c2 = sf*cpre + si*tanhf(gg);
      float h2 = so*tanhf(c2);
      c[t2]=c2; hout[t2]=h2;
    }
  }
}

// ---------------- hproj fp16 (R6/R8-proven) ----------------
__global__ __launch_bounds__(256) void hproj_h16_kernel(const unsigned short* __restrict__ Wh16,
                                                        const float* __restrict__ h,
                                                        float* __restrict__ a){
  __shared__ float4 hs4[512];
  int tid = threadIdx.x, wid = tid>>6, lane = tid&63;
  int j = blockIdx.x*4 + wid;
  const u16x8* W8 = (const u16x8*)(Wh16 + (size_t)j*HID);
  u16x8 wv[4];
  #pragma unroll
  for (int it=0; it<4; ++it) wv[it] = W8[it*64+lane];
  hs4[tid] = ((const float4*)h)[tid];
  hs4[tid+256] = ((const float4*)h)[tid+256];
  __syncthreads();
  float acc = 0.f;
  #pragma unroll
  for (int it=0; it<4; ++it){
    int idx = (it*64+lane)*2;
    float4 h0 = hs4[idx], h1 = hs4[idx+1];
    u16x8 w = wv[it];
    acc += h2f(w[0])*h0.x + h2f(w[1])*h0.y + h2f(w[2])*h0.z + h2f(w[3])*h0.w
         + h2f(w[4])*h1.x + h2f(w[5])*h1.y + h2f(w[6])*h1.z + h2f(w[7])*h1.w;
  }
  acc = wave_reduce(acc);
  if (lane==0) a[j] = acc;
}

// ---------------- finalize (R8-proven) ----------------
__global__ __launch_bounds__(512) void finalize_fused(const float* __restrict__ h,
                                                      const float* __restrict__ Wsoft,
                                                      const float* __restrict__ bsoft,
                                                      uint32_t* __restrict__ key_arr,
                                                      float* __restrict__ sc,
                                                      int* __restrict__ actions,
                                                      float* __restrict__ out){
  __shared__ float4 hs4[512];
  __shared__ float slog[11];
  int tid = threadIdx.x, wid = tid>>6, lane = tid&63;
  hs4[tid] = ((const float4*)h)[tid];
  __syncthreads();
  #pragma unroll
  for (int rep=0; rep<2; ++rep){
    int row = wid + rep*8;
    if (row < 11){
      const float4* W4 = (const float4*)(Wsoft + (size_t)row*HID);
      float s = 0.f;
      #pragma unroll
      for (int it=0; it<8; ++it) s += dot4(W4[it*64+lane], hs4[it*64+lane]);
      s = wave_reduce(s);
      if (lane==0) slog[row] = s + bsoft[row];
    }
  }
  __syncthreads();
  if (wid==0){
    float li = (lane<11) ? tanhf(slog[lane]*0.2f) : -3.0e38f;
    int act = sample_wave(li, 11, lane, key_arr, 27, true, sc, actions, 27);
    if (lane==0) out[27] = (float)act;
  }
  __syncthreads();
  if (tid==0){ out[28] = sc[0]; out[29] = sc[1]; }
  if (tid < 27) out[tid] = (float)actions[tid];
}

extern "C" void kernel_launch(void* const* d_in, const int* in_sizes, int n_in,
                              void* d_out, int out_size, void* d_ws, size_t ws_size,
                              hipStream_t stream) {
  const float* emb   = (const float*)d_in[0];
  const float* Wq    = (const float*)d_in[1];
  const float* Wh    = (const float*)d_in[2];
  const float* Wv    = (const float*)d_in[3];
  const float* Wsoft = (const float*)d_in[4];
  const float* bsoft = (const float*)d_in[5];
  const float* Wih   = (const float*)d_in[6];
  const float* Whh   = (const float*)d_in[7];
  const float* bih   = (const float*)d_in[8];
  const float* bhh   = (const float*)d_in[9];
  float* out = (float*)d_out;

  const size_t nWhh = (size_t)4*HID*HID;
  const size_t nWh  = (size_t)HID*HID;
  const size_t halfBytes = (nWhh + nWh) * 2;

  unsigned short* Whh16 = (unsigned short*)d_ws;
  unsigned short* Wh16  = Whh16 + nWhh;
  float* fbase = (float*)((char*)d_ws + halfBytes);

  float* h0      = fbase;
  float* h1      = h0 + HID;
  float* c       = h1 + HID;
  float* E       = c  + HID;
  float* P       = E  + 8*HID;
  float* a       = P  + 20*4*HID;
  float* sc      = a + HID;
  uint32_t* key_arr = (uint32_t*)(sc + 2);
  int* actions   = (int*)(key_arr + 58);

  {
    int nA8 = (int)(nWhh/8), nTot8 = (int)((nWhh+nWh)/8);
    conv_kernel<<<(nTot8+255)/256,256,0,stream>>>(Whh, Wh, Whh16, Wh16, nA8, nTot8);
  }
  eproj_kernel<<<512,256,0,stream>>>(emb, Wq, E, h0, c, sc, key_arr);
  pproj_kernel<<<1024,256,0,stream>>>(Wih, emb, bih, bhh, P);

  float* hbuf[2] = {h0, h1};
  int cur = 0, s = 0;
  for (int node = 0; node < 7; ++node){
    for (int i = 0; i < 4; ++i){
      int mode, kk=0, slot=0, xoff=0;
      if (s == 0){ mode = 0; }
      else {
        int ps = s-1, pi = ps%4, pn = ps/4;
        if (pi < 2){ mode = 1; kk = pn+2; slot = pn*2+pi; xoff = 0; }
        else       { mode = 2; kk = 11;  slot = 14+pn*2+(pi-2); xoff = 8; }
      }
      lstm_fused<<<512,512,0,stream>>>(Whh16, P, hbuf[cur], hbuf[cur^1], c,
                                       a, E, Wv, Wsoft, bsoft,
                                       key_arr, sc, actions,
                                       mode, kk, s-1, slot, xoff, 19);
      cur ^= 1;
      if (i < 2) hproj_h16_kernel<<<512,256,0,stream>>>(Wh16, hbuf[cur], a);
      s++;
    }
  }
  finalize_fused<<<1,512,0,stream>>>(hbuf[cur], Wsoft, bsoft, key_arr, sc, actions, out);
}

// Round 18
// 425.362 us; speedup vs baseline: 1.0953x; 1.0953x over previous
//
#include <hip/hip_runtime.h>
#include <stdint.h>
#include <string.h>

#define HID 2048

typedef __attribute__((ext_vector_type(8))) unsigned short u16x8;

__device__ __forceinline__ float h2f(unsigned short u){
  _Float16 f; __builtin_memcpy(&f, &u, 2); return (float)f;
}
__device__ __forceinline__ unsigned short f2h(float f){
  _Float16 g = (_Float16)f; unsigned short u; __builtin_memcpy(&u, &g, 2); return u;
}

// async global->LDS copy, 16B per lane; LDS dest = uniform base + lane*16 (HW)
typedef __attribute__((address_space(1))) const unsigned int gas_u32;
typedef __attribute__((address_space(3))) unsigned int las_u32;
__device__ __forceinline__ void gload16(const void* g, void* l){
  __builtin_amdgcn_global_load_lds((gas_u32*)g, (las_u32*)l, 16, 0, 0);
}

// ---------------- threefry2x32 (JAX partitionable; actions bit-exact R2-R17) ----------------
__device__ __forceinline__ uint32_t rotl32(uint32_t v, int r){ return (v<<r)|(v>>(32-r)); }

__device__ __forceinline__ void tf2x32(uint32_t k0, uint32_t k1, uint32_t x0, uint32_t x1,
                                       uint32_t& o0, uint32_t& o1){
  uint32_t ks2 = k0 ^ k1 ^ 0x1BD11BDAu;
  x0 += k0; x1 += k1;
  x0+=x1; x1=rotl32(x1,13); x1^=x0;
  x0+=x1; x1=rotl32(x1,15); x1^=x0;
  x0+=x1; x1=rotl32(x1,26); x1^=x0;
  x0+=x1; x1=rotl32(x1,6);  x1^=x0;
  x0+=k1; x1+=ks2+1u;
  x0+=x1; x1=rotl32(x1,17); x1^=x0;
  x0+=x1; x1=rotl32(x1,29); x1^=x0;
  x0+=x1; x1=rotl32(x1,16); x1^=x0;
  x0+=x1; x1=rotl32(x1,24); x1^=x0;
  x0+=ks2; x1+=k0+2u;
  x0+=x1; x1=rotl32(x1,13); x1^=x0;
  x0+=x1; x1=rotl32(x1,15); x1^=x0;
  x0+=x1; x1=rotl32(x1,26); x1^=x0;
  x0+=x1; x1=rotl32(x1,6);  x1^=x0;
  x0+=k0; x1+=k1+3u;
  x0+=x1; x1=rotl32(x1,17); x1^=x0;
  x0+=x1; x1=rotl32(x1,29); x1^=x0;
  x0+=x1; x1=rotl32(x1,16); x1^=x0;
  x0+=x1; x1=rotl32(x1,24); x1^=x0;
  x0+=k1; x1+=ks2+4u;
  x0+=x1; x1=rotl32(x1,13); x1^=x0;
  x0+=x1; x1=rotl32(x1,15); x1^=x0;
  x0+=x1; x1=rotl32(x1,26); x1^=x0;
  x0+=x1; x1=rotl32(x1,6);  x1^=x0;
  x0+=ks2; x1+=k0+5u;
  o0=x0; o1=x1;
}

__device__ __forceinline__ float wave_reduce(float v){
  #pragma unroll
  for (int s=32;s;s>>=1) v += __shfl_xor(v, s);
  return v;
}
__device__ __forceinline__ float dot4(float4 a, float4 b){
  return a.x*b.x + a.y*b.y + a.z*b.z + a.w*b.w;
}

// Wave-parallel sampler (R8-proven bit-exact). Returns argmax idx in ALL lanes.
__device__ __forceinline__ int sample_wave(float li, int kk, int lane,
                                           uint32_t* key_arr, int sidx, bool write,
                                           float* sc, int* actions, int slot){
  uint32_t k0 = key_arr[2*sidx], k1 = key_arr[2*sidx+1];
  uint32_t n0,n1,s0,s1;
  tf2x32(k0,k1,0u,0u,n0,n1);
  tf2x32(k0,k1,0u,1u,s0,s1);

  float m = li;
  #pragma unroll
  for (int s=32;s;s>>=1) m = fmaxf(m, __shfl_xor(m,s));
  float e = (lane<kk)? expf(li-m) : 0.f;
  float se = wave_reduce(e);
  float lse = logf(se);

  uint32_t y0,y1; tf2x32(s0,s1,0u,(uint32_t)lane,y0,y1);
  uint32_t bits = y0^y1;
  float f = __uint_as_float((bits>>9)|0x3f800000u) - 1.0f;
  float u = fmaxf(f, 1.17549435e-38f);
  float g = -logf(-logf(u));
  float z = (lane<kk)? li+g : -3.0e38f;
  int idx = lane;
  #pragma unroll
  for (int s=32;s;s>>=1){
    float zo = __shfl_xor(z,s); int io = __shfl_xor(idx,s);
    if (zo > z || (zo == z && io < idx)){ z = zo; idx = io; }
  }
  if (write){
    float lact = __shfl(li, idx);
    float lp = li-m-lse;
    float t = (lane<kk)? -lp*expf(lp) : 0.f;
    float ent = wave_reduce(t);
    if (lane==0){
      sc[0] += lact-m-lse;
      sc[1] += ent;
      actions[slot] = idx;
      key_arr[2*(sidx+1)]   = n0;
      key_arr[2*(sidx+1)+1] = n1;
    }
  }
  return idx;
}

// ---------------- weight conversion f32 -> f16 (Whh then Wh) ----------------
__global__ __launch_bounds__(256) void conv_kernel(const float* __restrict__ A,
                                                   const float* __restrict__ B,
                                                   unsigned short* __restrict__ oA,
                                                   unsigned short* __restrict__ oB,
                                                   int nA8, int nTot8){
  int i = blockIdx.x*256 + threadIdx.x;
  if (i >= nTot8) return;
  const float4* src; unsigned short* dst;
  if (i < nA8){ src = (const float4*)A + (size_t)i*2; dst = oA + (size_t)i*8; }
  else { int q = i - nA8; src = (const float4*)B + (size_t)q*2; dst = oB + (size_t)q*8; }
  float4 lo = src[0], hi = src[1];
  u16x8 o;
  o[0]=f2h(lo.x); o[1]=f2h(lo.y); o[2]=f2h(lo.z); o[3]=f2h(lo.w);
  o[4]=f2h(hi.x); o[5]=f2h(hi.y); o[6]=f2h(hi.z); o[7]=f2h(hi.w);
  *(u16x8*)dst = o;
}

// ---------------- eproj + init fold (R11-R16-proven) ----------------
__global__ __launch_bounds__(256) void eproj_kernel(const float* __restrict__ emb,
                                                    const float* __restrict__ Wq,
                                                    float* __restrict__ E,
                                                    float* __restrict__ h0,
                                                    float* __restrict__ c,
                                                    float* __restrict__ sc,
                                                    uint32_t* __restrict__ key_arr){
  if (blockIdx.x == 0){
    for (int r = threadIdx.x; r < HID; r += 256){ h0[r]=0.f; c[r]=0.f; }
    if (threadIdx.x == 0){ sc[0]=0.f; sc[1]=0.f; key_arr[0]=0u; key_arr[1]=42u; }
  }
  int w = (blockIdx.x*256 + threadIdx.x) >> 6;
  int lane = threadIdx.x & 63;
  if (w >= HID) return;
  const float4* W4 = (const float4*)(Wq + (size_t)w*HID);
  float acc[8];
  #pragma unroll
  for (int i=0;i<8;i++) acc[i]=0.f;
  #pragma unroll
  for (int it=0; it<8; ++it){
    float4 wv = W4[it*64 + lane];
    #pragma unroll
    for (int i=0;i<8;i++){
      float4 ev = ((const float4*)(emb + (size_t)i*HID))[it*64+lane];
      acc[i] += dot4(wv, ev);
    }
  }
  #pragma unroll
  for (int i=0;i<8;i++){
    float v = wave_reduce(acc[i]);
    if (lane==0) E[(size_t)i*HID + w] = v;
  }
}

// ---------------- pproj v5: async double-buffered LDS staging (R16-proven) ----------------
__global__ __launch_bounds__(256) void pproj_kernel(const float* __restrict__ Wih,
                                                    const float* __restrict__ emb,
                                                    const float* __restrict__ bih,
                                                    const float* __restrict__ bhh,
                                                    float* __restrict__ P){
  __shared__ float sbuf[2][19*256];   // 2 x 19456 B = 38912 B
  int tid = threadIdx.x, wid = tid>>6, lane = tid&63;
  int j0 = blockIdx.x*8 + wid*2, j1 = j0+1;
  float acc0[19], acc1[19];
  #pragma unroll
  for (int e=0;e<19;e++){ acc0[e]=0.f; acc1[e]=0.f; }

  for (int r = wid; r < 19; r += 4)
    gload16(emb + (size_t)r*HID + lane*4, (char*)&sbuf[0][r*256]);

  for (int ch = 0; ch < 8; ++ch){
    __syncthreads();
    if (ch < 7){
      float* nb = sbuf[(ch+1)&1];
      for (int r = wid; r < 19; r += 4)
        gload16(emb + (size_t)r*HID + (ch+1)*256 + lane*4, (char*)&nb[r*256]);
    }
    const float4* W0 = (const float4*)(Wih + (size_t)j0*HID + ch*256);
    const float4* W1 = (const float4*)(Wih + (size_t)j1*HID + ch*256);
    float4 w0 = W0[lane];
    float4 w1 = W1[lane];
    const float4* B4 = (const float4*)sbuf[ch&1];
    #pragma unroll
    for (int e=0;e<19;e++){
      float4 ev = B4[e*64 + lane];
      acc0[e] += dot4(w0, ev);
      acc1[e] += dot4(w1, ev);
    }
  }
  #pragma unroll
  for (int e=0;e<19;e++){ acc0[e]=wave_reduce(acc0[e]); acc1[e]=wave_reduce(acc1[e]); }
  if (lane==0){
    float b0 = bih[j0] + bhh[j0];
    float b1 = bih[j1] + bhh[j1];
    #pragma unroll
    for (int e=0;e<19;e++){
      P[(size_t)e*4*HID + j0] = acc0[e] + b0;
      P[(size_t)e*4*HID + j1] = acc1[e] + b1;
    }
    P[(size_t)19*4*HID + j0] = b0;
    P[(size_t)19*4*HID + j1] = b1;
  }
}

// ---------------- fused LSTM + pending sample (R16 body; only change: no sxi barrier) ----------------
// Wave 0 keeps `act` in registers after the butterfly; its lanes 0-3 run the pointwise
// tail directly (reading P[xi] and c[t2] from global exactly as R16 did). Waves 1-7
// exit after the compute barrier. Bit-exact vs R16.
__global__ __launch_bounds__(512,4) void lstm_fused(const unsigned short* __restrict__ Whh16,
                                                    const float* __restrict__ P,
                                                    const float* __restrict__ hin,
                                                    float* __restrict__ hout,
                                                    float* __restrict__ c,
                                                    const float* __restrict__ a,
                                                    const float* __restrict__ E,
                                                    const float* __restrict__ Wv,
                                                    const float* __restrict__ Wsoft,
                                                    const float* __restrict__ bsoft,
                                                    uint32_t* __restrict__ key_arr,
                                                    float* __restrict__ sc,
                                                    int* __restrict__ actions,
                                                    int mode, int k, int sidx, int slot,
                                                    int xoff, int xconst){
  __shared__ float4 hs4[512];
  __shared__ float red[8][4];
  __shared__ float slog[11];
  int tid = threadIdx.x, wid = tid>>6, lane = tid&63;
  hs4[tid] = ((const float4*)hin)[tid];
  int tl = wid & 3, khalf = wid >> 2;
  int t = blockIdx.x*4 + tl;
  u16x8 wv[4][2];
  #pragma unroll
  for (int g=0; g<4; ++g){
    const u16x8* wr = (const u16x8*)(Whh16 + ((size_t)(g*HID + t))*HID) + khalf*128;
    wv[g][0] = wr[lane];
    wv[g][1] = wr[64 + lane];
  }
  __syncthreads();   // hs4 ready

  // ---- matvec first (independent of pending sample) ----
  float4 hv[2][2];
  #pragma unroll
  for (int it=0; it<2; ++it){
    int idx = khalf*256 + (it*64+lane)*2;
    hv[it][0] = hs4[idx]; hv[it][1] = hs4[idx+1];
  }
  float acc[4] = {0.f,0.f,0.f,0.f};
  #pragma unroll
  for (int g=0; g<4; ++g){
    #pragma unroll
    for (int it=0; it<2; ++it){
      u16x8 w = wv[g][it];
      acc[g] += h2f(w[0])*hv[it][0].x + h2f(w[1])*hv[it][0].y
              + h2f(w[2])*hv[it][0].z + h2f(w[3])*hv[it][0].w
              + h2f(w[4])*hv[it][1].x + h2f(w[5])*hv[it][1].y
              + h2f(w[6])*hv[it][1].z + h2f(w[7])*hv[it][1].w;
    }
  }
  #pragma unroll
  for (int g=0; g<4; ++g){
    float v = wave_reduce(acc[g]);
    if (lane==0) red[wid][g] = v;
  }

  // ---- pending-sample logit rows (overlaps tail of other waves' matvec) ----
  if (mode == 1){
    if (wid < k){
      const float4* E4 = (const float4*)(E + (size_t)wid*HID);
      const float4* a4 = (const float4*)a;
      const float4* v4 = (const float4*)Wv;
      float s = 0.f;
      #pragma unroll
      for (int it=0; it<8; ++it){
        float4 ev = E4[it*64+lane];
        float4 av = a4[it*64+lane];
        float4 w  = v4[it*64+lane];
        s += tanhf(ev.x+av.x)*w.x + tanhf(ev.y+av.y)*w.y
           + tanhf(ev.z+av.z)*w.z + tanhf(ev.w+av.w)*w.w;
      }
      s = wave_reduce(s);
      if (lane==0) slog[wid] = s;
    }
  } else if (mode == 2){
    #pragma unroll
    for (int rep=0; rep<2; ++rep){
      int row = wid + rep*8;
      if (row < 11){
        const float4* W4 = (const float4*)(Wsoft + (size_t)row*HID);
        float s = 0.f;
        #pragma unroll
        for (int it=0; it<8; ++it) s += dot4(W4[it*64+lane], hs4[it*64+lane]);
        s = wave_reduce(s);
        if (lane==0) slog[row] = s + bsoft[row];
      }
    }
  }
  __syncthreads();   // red + slog ready (LAST barrier; waves 1-7 exit after this)

  if (wid == 0){
    int xi;
    if (mode == 0){
      xi = xconst;
    } else {
      int kk = (mode==1) ? k : 11;
      float li = -3.0e38f;
      if (lane < kk){
        float raw = slog[lane];
        li = (mode==1) ? 2.5f*tanhf(raw*0.2f) : tanhf(raw*0.2f);
      }
      int act = sample_wave(li, kk, lane, key_arr, sidx, blockIdx.x==0,
                            sc, actions, slot);
      xi = act + xoff;
    }
    if (lane < 4){
      int t2 = blockIdx.x*4 + lane;
      const float* Pr = P + (size_t)xi*4*HID;
      float gi = red[lane][0]+red[lane+4][0] + Pr[t2];
      float gf = red[lane][1]+red[lane+4][1] + Pr[HID+t2];
      float gg = red[lane][2]+red[lane+4][2] + Pr[2*HID+t2];
      float go = red[lane][3]+red[lane+4][3] + Pr[3*HID+t2];
      float si = 1.f/(1.f+expf(-gi));
      float sf = 1.f/(1.f+expf(-gf));
      float so = 1.f/(1.f+expf(-go));
      float c2 = sf*c[t2] + si*tanhf(gg);
      float h2 = so*tanhf(c2);
      c[t2]=c2; hout[t2]=h2;
    }
  }
}

// ---------------- hproj fp16 (R6/R8-proven) ----------------
__global__ __launch_bounds__(256) void hproj_h16_kernel(const unsigned short* __restrict__ Wh16,
                                                        const float* __restrict__ h,
                                                        float* __restrict__ a){
  __shared__ float4 hs4[512];
  int tid = threadIdx.x, wid = tid>>6, lane = tid&63;
  int j = blockIdx.x*4 + wid;
  const u16x8* W8 = (const u16x8*)(Wh16 + (size_t)j*HID);
  u16x8 wv[4];
  #pragma unroll
  for (int it=0; it<4; ++it) wv[it] = W8[it*64+lane];
  hs4[tid] = ((const float4*)h)[tid];
  hs4[tid+256] = ((const float4*)h)[tid+256];
  __syncthreads();
  float acc = 0.f;
  #pragma unroll
  for (int it=0; it<4; ++it){
    int idx = (it*64+lane)*2;
    float4 h0 = hs4[idx], h1 = hs4[idx+1];
    u16x8 w = wv[it];
    acc += h2f(w[0])*h0.x + h2f(w[1])*h0.y + h2f(w[2])*h0.z + h2f(w[3])*h0.w
         + h2f(w[4])*h1.x + h2f(w[5])*h1.y + h2f(w[6])*h1.z + h2f(w[7])*h1.w;
  }
  acc = wave_reduce(acc);
  if (lane==0) a[j] = acc;
}

// ---------------- finalize (R8-proven) ----------------
__global__ __launch_bounds__(512) void finalize_fused(const float* __restrict__ h,
                                                      const float* __restrict__ Wsoft,
                                                      const float* __restrict__ bsoft,
                                                      uint32_t* __restrict__ key_arr,
                                                      float* __restrict__ sc,
                                                      int* __restrict__ actions,
                                                      float* __restrict__ out){
  __shared__ float4 hs4[512];
  __shared__ float slog[11];
  int tid = threadIdx.x, wid = tid>>6, lane = tid&63;
  hs4[tid] = ((const float4*)h)[tid];
  __syncthreads();
  #pragma unroll
  for (int rep=0; rep<2; ++rep){
    int row = wid + rep*8;
    if (row < 11){
      const float4* W4 = (const float4*)(Wsoft + (size_t)row*HID);
      float s = 0.f;
      #pragma unroll
      for (int it=0; it<8; ++it) s += dot4(W4[it*64+lane], hs4[it*64+lane]);
      s = wave_reduce(s);
      if (lane==0) slog[row] = s + bsoft[row];
    }
  }
  __syncthreads();
  if (wid==0){
    float li = (lane<11) ? tanhf(slog[lane]*0.2f) : -3.0e38f;
    int act = sample_wave(li, 11, lane, key_arr, 27, true, sc, actions, 27);
    if (lane==0) out[27] = (float)act;
  }
  __syncthreads();
  if (tid==0){ out[28] = sc[0]; out[29] = sc[1]; }
  if (tid < 27) out[tid] = (float)actions[tid];
}

extern "C" void kernel_launch(void* const* d_in, const int* in_sizes, int n_in,
                              void* d_out, int out_size, void* d_ws, size_t ws_size,
                              hipStream_t stream) {
  const float* emb   = (const float*)d_in[0];
  const float* Wq    = (const float*)d_in[1];
  const float* Wh    = (const float*)d_in[2];
  const float* Wv    = (const float*)d_in[3];
  const float* Wsoft = (const float*)d_in[4];
  const float* bsoft = (const float*)d_in[5];
  const float* Wih   = (const float*)d_in[6];
  const float* Whh   = (const float*)d_in[7];
  const float* bih   = (const float*)d_in[8];
  const float* bhh   = (const float*)d_in[9];
  float* out = (float*)d_out;

  const size_t nWhh = (size_t)4*HID*HID;
  const size_t nWh  = (size_t)HID*HID;
  const size_t halfBytes = (nWhh + nWh) * 2;

  unsigned short* Whh16 = (unsigned short*)d_ws;
  unsigned short* Wh16  = Whh16 + nWhh;
  float* fbase = (float*)((char*)d_ws + halfBytes);

  float* h0      = fbase;
  float* h1      = h0 + HID;
  float* c       = h1 + HID;
  float* E       = c  + HID;
  float* P       = E  + 8*HID;
  float* a       = P  + 20*4*HID;
  float* sc      = a + HID;
  uint32_t* key_arr = (uint32_t*)(sc + 2);
  int* actions   = (int*)(key_arr + 58);

  {
    int nA8 = (int)(nWhh/8), nTot8 = (int)((nWhh+nWh)/8);
    conv_kernel<<<(nTot8+255)/256,256,0,stream>>>(Whh, Wh, Whh16, Wh16, nA8, nTot8);
  }
  eproj_kernel<<<512,256,0,stream>>>(emb, Wq, E, h0, c, sc, key_arr);
  pproj_kernel<<<1024,256,0,stream>>>(Wih, emb, bih, bhh, P);

  float* hbuf[2] = {h0, h1};
  int cur = 0, s = 0;
  for (int node = 0; node < 7; ++node){
    for (int i = 0; i < 4; ++i){
      int mode, kk=0, slot=0, xoff=0;
      if (s == 0){ mode = 0; }
      else {
        int ps = s-1, pi = ps%4, pn = ps/4;
        if (pi < 2){ mode = 1; kk = pn+2; slot = pn*2+pi; xoff = 0; }
        else       { mode = 2; kk = 11;  slot = 14+pn*2+(pi-2); xoff = 8; }
      }
      lstm_fused<<<512,512,0,stream>>>(Whh16, P, hbuf[cur], hbuf[cur^1], c,
                                       a, E, Wv, Wsoft, bsoft,
                                       key_arr, sc, actions,
                                       mode, kk, s-1, slot, xoff, 19);
      cur ^= 1;
      if (i < 2) hproj_h16_kernel<<<512,256,0,stream>>>(Wh16, hbuf[cur], a);
      s++;
    }
  }
  finalize_fused<<<1,512,0,stream>>>(hbuf[cur], Wsoft, bsoft, key_arr, sc, actions, out);
}